// Round 11
// baseline (97348.621 us; speedup 1.0000x reference)
//
#include <hip/hip_runtime.h>
#include <math.h>

#define BSZ 1024
#define NNODE 200
#define DH 512
#define DK 512
#define NSTEP 200
#define G 4       // batch rows per block
#define TPB 1024

// ---------------- threefry2x32 (JAX-exact, partitionable mode) ----------------
__device__ __forceinline__ unsigned rotl32(unsigned x, int r) {
  return (x << r) | (x >> (32 - r));
}

__device__ __forceinline__ void tf2x32(unsigned k0, unsigned k1,
                                       unsigned c0, unsigned c1,
                                       unsigned& o0, unsigned& o1) {
  unsigned ks2 = k0 ^ k1 ^ 0x1BD11BDAu;
  unsigned x0 = c0 + k0, x1 = c1 + k1;
#define TF_RND(r) { x0 += x1; x1 = rotl32(x1, (r)); x1 ^= x0; }
  TF_RND(13) TF_RND(15) TF_RND(26) TF_RND(6)
  x0 += k1;  x1 += ks2 + 1u;
  TF_RND(17) TF_RND(29) TF_RND(16) TF_RND(24)
  x0 += ks2; x1 += k0 + 2u;
  TF_RND(13) TF_RND(15) TF_RND(26) TF_RND(6)
  x0 += k0;  x1 += k1 + 3u;
  TF_RND(17) TF_RND(29) TF_RND(16) TF_RND(24)
  x0 += k1;  x1 += ks2 + 4u;
  TF_RND(13) TF_RND(15) TF_RND(26) TF_RND(6)
  x0 += ks2; x1 += k0 + 5u;
#undef TF_RND
  o0 = x0; o1 = x1;
}

__device__ __forceinline__ void step_key(int i, unsigned& k0, unsigned& k1) {
  tf2x32(0u, 42u, 0u, (unsigned)i, k0, k1);
}
__device__ __forceinline__ unsigned elem_bits(unsigned k0, unsigned k1, unsigned m) {
  unsigned o0, o1;
  tf2x32(k0, k1, 0u, m, o0, o1);
  return o0 ^ o1;
}

// -------- XLA f32 tanh (EmitFastTanh, with_fma=true -> fmuladd Horner) -------
__device__ __forceinline__ float xla_tanh_f32(float x) {
  const float kMax = 7.90531110763549805f;
  float xc = fminf(fmaxf(x, -kMax), kMax);
  float x2 = xc * xc;
  float p = -2.76076847742355e-16f;
  p = __builtin_fmaf(x2, p, 2.00018790482477e-13f);
  p = __builtin_fmaf(x2, p, -8.60467152213735e-11f);
  p = __builtin_fmaf(x2, p, 5.12229709037114e-08f);
  p = __builtin_fmaf(x2, p, 1.48572235717979e-05f);
  p = __builtin_fmaf(x2, p, 6.37261928875436e-04f);
  p = __builtin_fmaf(x2, p, 4.89352455891786e-03f);
  float num = xc * p;
  float q = 1.19825839466702e-06f;
  q = __builtin_fmaf(x2, q, 1.18534705686654e-04f);
  q = __builtin_fmaf(x2, q, 2.26843463243900e-03f);
  q = __builtin_fmaf(x2, q, 4.89352518554385e-03f);
  float r = num / q;
  return (fabsf(x) < 0.0004f) ? x : r;
}

// ---------------- XLA f32 log (Cephes, plain fmul/fadd as in VF32Log) --------
__device__ __forceinline__ float xla_log_f32(float x) {
#pragma clang fp contract(off)
  unsigned bits = __float_as_uint(x);
  int e = (int)((bits >> 23) & 0xffu) - 126;          // x = m * 2^e, m in [0.5,1)
  float m = __uint_as_float((bits & 0x007fffffu) | 0x3f000000u);
  bool c = m < 0.707106781186547524f;                 // sqrt(0.5)
  e = c ? (e - 1) : e;
  m = c ? (m + m) : m;
  m = m - 1.0f;
  float z = m * m;
  float y = 7.0376836292e-2f;
  y = y * m + (-1.1514610310e-1f);
  y = y * m + 1.1676998740e-1f;
  y = y * m + (-1.2420140846e-1f);
  y = y * m + 1.4249322787e-1f;
  y = y * m + (-1.6668057665e-1f);
  y = y * m + 2.0000714765e-1f;
  y = y * m + (-2.4999993993e-1f);
  y = y * m + 3.3333331174e-1f;
  y = y * m;
  y = y * z;
  float ef = (float)e;
  float t1 = ef * (-2.12194440e-4f);
  y = y + t1;
  float t2 = z * 0.5f;
  y = y - t2;
  float r = m + y;
  float t3 = ef * 0.693359375f;
  r = r + t3;
  return r;
}

// ---------------- U-phase helpers: static-index reg buffers ------------------
__device__ __forceinline__ void load32(float (&buf)[32], const float* __restrict__ Kb,
                                       int grp, int tl) {
#pragma unroll
  for (int j = 0; j < 32; j++)
    buf[j] = Kb[(size_t)(grp * 32 + j) * NNODE + tl];
}
// accumulate 2 chunks of 16 in k-ascending mod-16 lane order (bit-exact R7 order)
__device__ __forceinline__ void comp32(const float (&buf)[32], float (&l)[16],
                                       const float* qrow, int grp) {
#pragma clang fp contract(off)
#pragma unroll
  for (int cc = 0; cc < 2; cc++) {
#pragma unroll
    for (int u = 0; u < 16; u++) {
      float prod = buf[cc * 16 + u] * qrow[grp * 32 + cc * 16 + u];  // mul rounding
      l[u] = l[u] + prod;                                            // then add
    }
  }
}

// ---------------- setup kernels (f32, gold-faithful orders) ----------------

__global__ void k_hbar(const float* __restrict__ H, float* __restrict__ Hbar) {
#pragma clang fp contract(off)
  int idx = blockIdx.x * 256 + threadIdx.x;  // 1024*512
  int b = idx >> 9, d = idx & 511;
  const float* p = H + (size_t)b * NNODE * DH + d;
  float s = 0.0f;
  for (int n = 0; n < NNODE; n++) s = s + p[(size_t)n * DH];
  Hbar[idx] = s / 200.0f;
}

// KT[b][k][n] = FMA-chain over d ascending of H[b,n,d]*WK[d,k]  (transposed layout)
__global__ __launch_bounds__(256) void k_K(const float* __restrict__ H,
                                           const float* __restrict__ WK,
                                           float* __restrict__ KT) {
  __shared__ float hr[8][DH];        // 16 KiB
  __shared__ float ts[DK * 9];       // retile pad-9, conflict-free
  int g = blockIdx.x;                // 1024*25 blocks, 8 rows each
  int b = g / 25;
  int r0 = (g % 25) * 8;
  int t = threadIdx.x;
  const float* Hb = H + (size_t)b * NNODE * DH + (size_t)r0 * DH;
  for (int e = t; e < 8 * DH; e += 256) hr[e >> 9][e & 511] = Hb[e];
  __syncthreads();
  int k0 = t, k1 = t + 256;
  float a[8][2];
#pragma unroll
  for (int r = 0; r < 8; r++) { a[r][0] = 0.0f; a[r][1] = 0.0f; }
  for (int d = 0; d < DH; d++) {
    float w0 = WK[(size_t)d * DK + k0], w1 = WK[(size_t)d * DK + k1];
#pragma unroll
    for (int r = 0; r < 8; r++) {
      a[r][0] = __builtin_fmaf(hr[r][d], w0, a[r][0]);
      a[r][1] = __builtin_fmaf(hr[r][d], w1, a[r][1]);
    }
  }
#pragma unroll
  for (int r = 0; r < 8; r++) {
    ts[k0 * 9 + r] = a[r][0];
    ts[k1 * 9 + r] = a[r][1];
  }
  __syncthreads();
  float* Ko = KT + (size_t)b * DK * NNODE + r0;
  for (int i = t; i < DK * 8; i += 256) {
    int k = i >> 3, r = i & 7;
    Ko[(size_t)k * NNODE + r] = ts[k * 9 + r];
  }
}

// acc[b][j] = FMA-chain k=0..511 of Hbar[b,k]*WQ[k,j] (prefix of the 1536-chain)
__global__ __launch_bounds__(256) void k_acc512(const float* __restrict__ Hbar,
                                                const float* __restrict__ WQ,
                                                float* __restrict__ acc) {
  __shared__ float hb[DH];
  int b = blockIdx.x, t = threadIdx.x;
  for (int e = t; e < DH; e += 256) hb[e] = Hbar[(size_t)b * DH + e];
  __syncthreads();
  int j0 = t, j1 = t + 256;
  float a0 = 0.0f, a1 = 0.0f;
  for (int k = 0; k < DH; k++) {
    float w0 = WQ[(size_t)k * DK + j0], w1 = WQ[(size_t)k * DK + j1];
    a0 = __builtin_fmaf(hb[k], w0, a0);
    a1 = __builtin_fmaf(hb[k], w1, a1);
  }
  acc[(size_t)b * DK + j0] = a0;
  acc[(size_t)b * DK + j1] = a1;
}

// ---------------- the fused 200-step decoder: one block owns G batch rows ----
__global__ __launch_bounds__(TPB) void k_mega(const float* __restrict__ KT,
                                              const float* __restrict__ acc,
                                              const float* __restrict__ WQ,
                                              const float* __restrict__ H,
                                              const float* __restrict__ v1,
                                              const float* __restrict__ vf,
                                              int* __restrict__ out) {
  __shared__ float hpI[DH][G];     // interleaved [k][bb] : current pick
  __shared__ float hp0I[DH][G];    // first pick (frozen after step 0)
  __shared__ float Qs[G][DK];
  __shared__ float accs[G][DK];
  __shared__ float zl[G][NNODE];
  int t = threadIdx.x;
  int b0 = blockIdx.x * G;
  int bb = t >> 8;                 // quarter owns batch row b0+bb
  int tl = t & 255;
  int b = b0 + bb;
  const float* Kb = KT + (size_t)b * DK * NNODE;
  const float* qrow = &Qs[bb][0];

  for (int e = t; e < G * DK; e += TPB) {
    int b2 = e >> 9, j = e & 511;
    accs[b2][j] = acc[(size_t)(b0 + b2) * DK + j];
  }
  for (int e = t; e < DH; e += TPB) {
    float a = v1[e], bv = vf[e];
#pragma unroll
    for (int b2 = 0; b2 < G; b2++) { hpI[e][b2] = a; hp0I[e][b2] = bv; }
  }
  __syncthreads();

  for (int step = 0; step < NSTEP; step++) {
    float A[32], B[32];
    // step-top K prefetch: waves with no Q work get their loads in flight
    // during the Q phase (they just hold at the barrier while data streams in).
    if (t >= 512 && tl < NNODE) { load32(A, Kb, 0, tl); load32(B, Kb, 1, tl); }

    // ---- Q phase (threads 0..511): thread owns column j=t; 4 chains.
    if (t < 512) {
      float a0 = accs[0][t], a1 = accs[1][t], a2 = accs[2][t], a3 = accs[3][t];
      const float* Wp = WQ + (size_t)512 * DK + t;
      for (int k = 0; k < DH; k += 4) {
        float w0 = Wp[(size_t)(k + 0) * DK];
        float w1 = Wp[(size_t)(k + 1) * DK];
        float w2 = Wp[(size_t)(k + 2) * DK];
        float w3 = Wp[(size_t)(k + 3) * DK];
        float4 h0 = *(const float4*)&hpI[k + 0][0];
        float4 h1 = *(const float4*)&hpI[k + 1][0];
        float4 h2 = *(const float4*)&hpI[k + 2][0];
        float4 h3 = *(const float4*)&hpI[k + 3][0];
        a0 = __builtin_fmaf(h0.x, w0, a0); a1 = __builtin_fmaf(h0.y, w0, a1);
        a2 = __builtin_fmaf(h0.z, w0, a2); a3 = __builtin_fmaf(h0.w, w0, a3);
        a0 = __builtin_fmaf(h1.x, w1, a0); a1 = __builtin_fmaf(h1.y, w1, a1);
        a2 = __builtin_fmaf(h1.z, w1, a2); a3 = __builtin_fmaf(h1.w, w1, a3);
        a0 = __builtin_fmaf(h2.x, w2, a0); a1 = __builtin_fmaf(h2.y, w2, a1);
        a2 = __builtin_fmaf(h2.z, w2, a2); a3 = __builtin_fmaf(h2.w, w2, a3);
        a0 = __builtin_fmaf(h3.x, w3, a0); a1 = __builtin_fmaf(h3.y, w3, a1);
        a2 = __builtin_fmaf(h3.z, w3, a2); a3 = __builtin_fmaf(h3.w, w3, a3);
      }
      const float* Wp2 = WQ + (size_t)1024 * DK + t;
      for (int k = 0; k < DH; k += 4) {
        float w0 = Wp2[(size_t)(k + 0) * DK];
        float w1 = Wp2[(size_t)(k + 1) * DK];
        float w2 = Wp2[(size_t)(k + 2) * DK];
        float w3 = Wp2[(size_t)(k + 3) * DK];
        float4 h0 = *(const float4*)&hp0I[k + 0][0];
        float4 h1 = *(const float4*)&hp0I[k + 1][0];
        float4 h2 = *(const float4*)&hp0I[k + 2][0];
        float4 h3 = *(const float4*)&hp0I[k + 3][0];
        a0 = __builtin_fmaf(h0.x, w0, a0); a1 = __builtin_fmaf(h0.y, w0, a1);
        a2 = __builtin_fmaf(h0.z, w0, a2); a3 = __builtin_fmaf(h0.w, w0, a3);
        a0 = __builtin_fmaf(h1.x, w1, a0); a1 = __builtin_fmaf(h1.y, w1, a1);
        a2 = __builtin_fmaf(h1.z, w1, a2); a3 = __builtin_fmaf(h1.w, w1, a3);
        a0 = __builtin_fmaf(h2.x, w2, a0); a1 = __builtin_fmaf(h2.y, w2, a1);
        a2 = __builtin_fmaf(h2.z, w2, a2); a3 = __builtin_fmaf(h2.w, w2, a3);
        a0 = __builtin_fmaf(h3.x, w3, a0); a1 = __builtin_fmaf(h3.y, w3, a1);
        a2 = __builtin_fmaf(h3.z, w3, a2); a3 = __builtin_fmaf(h3.w, w3, a3);
      }
      Qs[0][t] = a0; Qs[1][t] = a1; Qs[2][t] = a2; Qs[3][t] = a3;
    }
    __syncthreads();   // Qs ready

    // ---- U/z phase: quarter bb, lane tl; A/B software-pipelined K stream.
    if (tl < NNODE) {
#pragma clang fp contract(off)
      if (t < 512) { load32(A, Kb, 0, tl); load32(B, Kb, 1, tl); }
      float l[16];
#pragma unroll
      for (int j = 0; j < 16; j++) l[j] = 0.0f;
#pragma unroll
      for (int g = 0; g < 16; g += 2) {    // 16 groups of 32 k, ascending
        comp32(A, l, qrow, g);
        if (g + 2 < 16) load32(A, Kb, g + 2, tl);
        comp32(B, l, qrow, g + 1);
        if (g + 3 < 16) load32(B, Kb, g + 3, tl);
      }
      // shuffle-halving horizontal reduce over 16 lanes:
#pragma unroll
      for (int j = 0; j < 8; j++) l[j] = l[j] + l[j + 8];
#pragma unroll
      for (int j = 0; j < 4; j++) l[j] = l[j] + l[j + 4];
#pragma unroll
      for (int j = 0; j < 2; j++) l[j] = l[j] + l[j + 2];
      float U = l[0] + l[1];
      const float inv = 1.0f / sqrtf(512.0f);
      float u = U * inv;
      float logit = 10.0f * xla_tanh_f32(u);
      unsigned kk0, kk1;
      step_key(step, kk0, kk1);
      unsigned bits = elem_bits(kk0, kk1, (unsigned)(b * NNODE + tl));
      unsigned fb = (bits >> 9) | 0x3F800000u;
      float uf = __uint_as_float(fb) - 1.0f;    // [0,1), exact
      const float tinyf = 1.17549435e-38f;
      float v = uf * 1.0f;
      v = v + tinyf;
      v = fmaxf(tinyf, v);
      float L1 = xla_log_f32(v);
      float gmb = -xla_log_f32(-L1);
      zl[bb][tl] = gmb + logit;
    }
    __syncthreads();   // zl ready

    // ---- argmax: EVERY wave reduces its quarter redundantly (no extra barrier)
    int pi;
    {
      float bv = -__builtin_inff();
      int bi = 0;
      for (int n = (tl & 63); n < NNODE; n += 64) {
        float zv = zl[bb][n];
        if (zv > bv) { bv = zv; bi = n; }
      }
      for (int off = 32; off; off >>= 1) {
        float ov = __shfl_down(bv, off);
        int   oi = __shfl_down(bi, off);
        if (ov > bv || (ov == bv && oi < bi)) { bv = ov; bi = oi; }
      }
      pi = __shfl(bi, 0);   // broadcast wave result (identical across waves)
    }
    if (tl == 0) {
      out[b * (NSTEP + 1) + step + 1] = pi;
      if (step == 0) out[b * (NSTEP + 1)] = pi;  // duplicated step-0 pick
    }
    {   // gather H[b, pi] into hpI (exact copy)
      const float* src = H + ((size_t)b * NNODE + pi) * DH;
      for (int e = tl; e < DH; e += 256) hpI[e][bb] = src[e];
    }
    __syncthreads();   // hpI ready
    if (step == 0) {   // freeze H_pi_1 = step-0 pick
      for (int e = t; e < DH * G; e += TPB) hp0I[e >> 2][e & 3] = hpI[e >> 2][e & 3];
      __syncthreads();
    }
  }
}

extern "C" void kernel_launch(void* const* d_in, const int* in_sizes, int n_in,
                              void* d_out, int out_size, void* d_ws, size_t ws_size,
                              hipStream_t stream) {
  (void)in_sizes; (void)n_in; (void)out_size; (void)ws_size;
  const float* H  = (const float*)d_in[1];
  const float* WQ = (const float*)d_in[2];
  const float* WK = (const float*)d_in[3];
  const float* v1 = (const float*)d_in[4];
  const float* vf = (const float*)d_in[5];
  int* out = (int*)d_out;

  float* ws = (float*)d_ws;
  const size_t KSZ = (size_t)BSZ * NNODE * DK;  // 419.4 MB
  const size_t S = (size_t)BSZ * 512;
  float* KT   = ws;
  float* Hbar = ws + KSZ;
  float* acc  = ws + KSZ + S;

  k_hbar  <<<2048, 256, 0, stream>>>(H, Hbar);
  k_K     <<<BSZ * 25, 256, 0, stream>>>(H, WK, KT);
  k_acc512<<<BSZ, 256, 0, stream>>>(Hbar, WQ, acc);
  k_mega  <<<BSZ / G, TPB, 0, stream>>>(KT, acc, WQ, H, v1, vf, out);
}

// Round 12
// 29590.192 us; speedup vs baseline: 3.2899x; 3.2899x over previous
//
#include <hip/hip_runtime.h>
#include <math.h>

#define BSZ 1024
#define NNODE 200
#define DH 512
#define DK 512
#define NSTEP 200
#define G 4       // batch rows per block
#define TPB 1024

// ---------------- threefry2x32 (JAX-exact, partitionable mode) ----------------
__device__ __forceinline__ unsigned rotl32(unsigned x, int r) {
  return (x << r) | (x >> (32 - r));
}

__device__ __forceinline__ void tf2x32(unsigned k0, unsigned k1,
                                       unsigned c0, unsigned c1,
                                       unsigned& o0, unsigned& o1) {
  unsigned ks2 = k0 ^ k1 ^ 0x1BD11BDAu;
  unsigned x0 = c0 + k0, x1 = c1 + k1;
#define TF_RND(r) { x0 += x1; x1 = rotl32(x1, (r)); x1 ^= x0; }
  TF_RND(13) TF_RND(15) TF_RND(26) TF_RND(6)
  x0 += k1;  x1 += ks2 + 1u;
  TF_RND(17) TF_RND(29) TF_RND(16) TF_RND(24)
  x0 += ks2; x1 += k0 + 2u;
  TF_RND(13) TF_RND(15) TF_RND(26) TF_RND(6)
  x0 += k0;  x1 += k1 + 3u;
  TF_RND(17) TF_RND(29) TF_RND(16) TF_RND(24)
  x0 += k1;  x1 += ks2 + 4u;
  TF_RND(13) TF_RND(15) TF_RND(26) TF_RND(6)
  x0 += ks2; x1 += k0 + 5u;
#undef TF_RND
  o0 = x0; o1 = x1;
}

__device__ __forceinline__ void step_key(int i, unsigned& k0, unsigned& k1) {
  tf2x32(0u, 42u, 0u, (unsigned)i, k0, k1);
}
__device__ __forceinline__ unsigned elem_bits(unsigned k0, unsigned k1, unsigned m) {
  unsigned o0, o1;
  tf2x32(k0, k1, 0u, m, o0, o1);
  return o0 ^ o1;
}

// -------- XLA f32 tanh (EmitFastTanh, with_fma=true -> fmuladd Horner) -------
__device__ __forceinline__ float xla_tanh_f32(float x) {
  const float kMax = 7.90531110763549805f;
  float xc = fminf(fmaxf(x, -kMax), kMax);
  float x2 = xc * xc;
  float p = -2.76076847742355e-16f;
  p = __builtin_fmaf(x2, p, 2.00018790482477e-13f);
  p = __builtin_fmaf(x2, p, -8.60467152213735e-11f);
  p = __builtin_fmaf(x2, p, 5.12229709037114e-08f);
  p = __builtin_fmaf(x2, p, 1.48572235717979e-05f);
  p = __builtin_fmaf(x2, p, 6.37261928875436e-04f);
  p = __builtin_fmaf(x2, p, 4.89352455891786e-03f);
  float num = xc * p;
  float q = 1.19825839466702e-06f;
  q = __builtin_fmaf(x2, q, 1.18534705686654e-04f);
  q = __builtin_fmaf(x2, q, 2.26843463243900e-03f);
  q = __builtin_fmaf(x2, q, 4.89352518554385e-03f);
  float r = num / q;
  return (fabsf(x) < 0.0004f) ? x : r;
}

// ---------------- XLA f32 log (Cephes, plain fmul/fadd as in VF32Log) --------
__device__ __forceinline__ float xla_log_f32(float x) {
#pragma clang fp contract(off)
  unsigned bits = __float_as_uint(x);
  int e = (int)((bits >> 23) & 0xffu) - 126;          // x = m * 2^e, m in [0.5,1)
  float m = __uint_as_float((bits & 0x007fffffu) | 0x3f000000u);
  bool c = m < 0.707106781186547524f;                 // sqrt(0.5)
  e = c ? (e - 1) : e;
  m = c ? (m + m) : m;
  m = m - 1.0f;
  float z = m * m;
  float y = 7.0376836292e-2f;
  y = y * m + (-1.1514610310e-1f);
  y = y * m + 1.1676998740e-1f;
  y = y * m + (-1.2420140846e-1f);
  y = y * m + 1.4249322787e-1f;
  y = y * m + (-1.6668057665e-1f);
  y = y * m + 2.0000714765e-1f;
  y = y * m + (-2.4999993993e-1f);
  y = y * m + 3.3333331174e-1f;
  y = y * m;
  y = y * z;
  float ef = (float)e;
  float t1 = ef * (-2.12194440e-4f);
  y = y + t1;
  float t2 = z * 0.5f;
  y = y - t2;
  float r = m + y;
  float t3 = ef * 0.693359375f;
  r = r + t3;
  return r;
}

// ---------------- setup kernels (f32, gold-faithful orders) ----------------

__global__ void k_hbar(const float* __restrict__ H, float* __restrict__ Hbar) {
#pragma clang fp contract(off)
  int idx = blockIdx.x * 256 + threadIdx.x;  // 1024*512
  int b = idx >> 9, d = idx & 511;
  const float* p = H + (size_t)b * NNODE * DH + d;
  float s = 0.0f;
  for (int n = 0; n < NNODE; n++) s = s + p[(size_t)n * DH];
  Hbar[idx] = s / 200.0f;
}

// KT4[b][c][n][j] = K[b][n][4c+j], K = FMA-chain over d ascending (Eigen model).
// float4-interleaved transposed layout: lane n loads 4 consecutive k per 16B.
__global__ __launch_bounds__(256) void k_K(const float* __restrict__ H,
                                           const float* __restrict__ WK,
                                           float* __restrict__ KT) {
  __shared__ float hr[8][DH];        // 16 KiB
  __shared__ float ts[DK * 9];       // retile pad-9, conflict-free
  int g = blockIdx.x;                // 1024*25 blocks, 8 rows each
  int b = g / 25;
  int r0 = (g % 25) * 8;
  int t = threadIdx.x;
  const float* Hb = H + (size_t)b * NNODE * DH + (size_t)r0 * DH;
  for (int e = t; e < 8 * DH; e += 256) hr[e >> 9][e & 511] = Hb[e];
  __syncthreads();
  int k0 = t, k1 = t + 256;
  float a[8][2];
#pragma unroll
  for (int r = 0; r < 8; r++) { a[r][0] = 0.0f; a[r][1] = 0.0f; }
  for (int d = 0; d < DH; d++) {
    float w0 = WK[(size_t)d * DK + k0], w1 = WK[(size_t)d * DK + k1];
#pragma unroll
    for (int r = 0; r < 8; r++) {
      a[r][0] = __builtin_fmaf(hr[r][d], w0, a[r][0]);
      a[r][1] = __builtin_fmaf(hr[r][d], w1, a[r][1]);
    }
  }
#pragma unroll
  for (int r = 0; r < 8; r++) {
    ts[k0 * 9 + r] = a[r][0];
    ts[k1 * 9 + r] = a[r][1];
  }
  __syncthreads();
  float* Ko = KT + (size_t)b * DK * NNODE;
  for (int i = t; i < (DK / 4) * 8; i += 256) {   // 1024 (c,r) pairs
    int c = i >> 3, r = i & 7;
    float4 v = make_float4(ts[(4 * c + 0) * 9 + r], ts[(4 * c + 1) * 9 + r],
                           ts[(4 * c + 2) * 9 + r], ts[(4 * c + 3) * 9 + r]);
    *(float4*)(Ko + ((size_t)c * NNODE + (r0 + r)) * 4) = v;
  }
}

// acc[b][j] = FMA-chain k=0..511 of Hbar[b,k]*WQ[k,j] (prefix of the 1536-chain)
__global__ __launch_bounds__(256) void k_acc512(const float* __restrict__ Hbar,
                                                const float* __restrict__ WQ,
                                                float* __restrict__ acc) {
  __shared__ float hb[DH];
  int b = blockIdx.x, t = threadIdx.x;
  for (int e = t; e < DH; e += 256) hb[e] = Hbar[(size_t)b * DH + e];
  __syncthreads();
  int j0 = t, j1 = t + 256;
  float a0 = 0.0f, a1 = 0.0f;
  for (int k = 0; k < DH; k++) {
    float w0 = WQ[(size_t)k * DK + j0], w1 = WQ[(size_t)k * DK + j1];
    a0 = __builtin_fmaf(hb[k], w0, a0);
    a1 = __builtin_fmaf(hb[k], w1, a1);
  }
  acc[(size_t)b * DK + j0] = a0;
  acc[(size_t)b * DK + j1] = a1;
}

// ---------------- the fused 200-step decoder: one block owns G batch rows ----
// __launch_bounds__(TPB, 4): 16-wave block => 4 waves/SIMD, VGPR cap 128.
__global__ __launch_bounds__(TPB, 4) void k_mega(const float* __restrict__ KT,
                                                 const float* __restrict__ acc,
                                                 const float* __restrict__ WQ,
                                                 const float* __restrict__ H,
                                                 const float* __restrict__ v1,
                                                 const float* __restrict__ vf,
                                                 int* __restrict__ out) {
  __shared__ float hpI[DH][G];     // interleaved [k][bb] : current pick
  __shared__ float hp0I[DH][G];    // first pick (frozen after step 0)
  __shared__ float Qs[G][DK];
  __shared__ float accs[G][DK];
  __shared__ float zl[G][NNODE];
  int t = threadIdx.x;
  int b0 = blockIdx.x * G;
  int bb = t >> 8;                 // quarter owns batch row b0+bb
  int tl = t & 255;
  int b = b0 + bb;
  const float4* Kb4 = (const float4*)(KT + (size_t)b * DK * NNODE) + tl;  // +n
  const float* qrow = &Qs[bb][0];

  for (int e = t; e < G * DK; e += TPB) {
    int b2 = e >> 9, j = e & 511;
    accs[b2][j] = acc[(size_t)(b0 + b2) * DK + j];
  }
  for (int e = t; e < DH; e += TPB) {
    float a = v1[e], bv = vf[e];
#pragma unroll
    for (int b2 = 0; b2 < G; b2++) { hpI[e][b2] = a; hp0I[e][b2] = bv; }
  }
  __syncthreads();

  for (int step = 0; step < NSTEP; step++) {
    // ---- Q phase (threads 0..511): thread owns column j=t; 4 chains.
    if (t < 512) {
      float a0 = accs[0][t], a1 = accs[1][t], a2 = accs[2][t], a3 = accs[3][t];
      const float* Wp = WQ + (size_t)512 * DK + t;
      for (int k = 0; k < DH; k += 4) {
        float w0 = Wp[(size_t)(k + 0) * DK];
        float w1 = Wp[(size_t)(k + 1) * DK];
        float w2 = Wp[(size_t)(k + 2) * DK];
        float w3 = Wp[(size_t)(k + 3) * DK];
        float4 h0 = *(const float4*)&hpI[k + 0][0];
        float4 h1 = *(const float4*)&hpI[k + 1][0];
        float4 h2 = *(const float4*)&hpI[k + 2][0];
        float4 h3 = *(const float4*)&hpI[k + 3][0];
        a0 = __builtin_fmaf(h0.x, w0, a0); a1 = __builtin_fmaf(h0.y, w0, a1);
        a2 = __builtin_fmaf(h0.z, w0, a2); a3 = __builtin_fmaf(h0.w, w0, a3);
        a0 = __builtin_fmaf(h1.x, w1, a0); a1 = __builtin_fmaf(h1.y, w1, a1);
        a2 = __builtin_fmaf(h1.z, w1, a2); a3 = __builtin_fmaf(h1.w, w1, a3);
        a0 = __builtin_fmaf(h2.x, w2, a0); a1 = __builtin_fmaf(h2.y, w2, a1);
        a2 = __builtin_fmaf(h2.z, w2, a2); a3 = __builtin_fmaf(h2.w, w2, a3);
        a0 = __builtin_fmaf(h3.x, w3, a0); a1 = __builtin_fmaf(h3.y, w3, a1);
        a2 = __builtin_fmaf(h3.z, w3, a2); a3 = __builtin_fmaf(h3.w, w3, a3);
      }
      const float* Wp2 = WQ + (size_t)1024 * DK + t;
      for (int k = 0; k < DH; k += 4) {
        float w0 = Wp2[(size_t)(k + 0) * DK];
        float w1 = Wp2[(size_t)(k + 1) * DK];
        float w2 = Wp2[(size_t)(k + 2) * DK];
        float w3 = Wp2[(size_t)(k + 3) * DK];
        float4 h0 = *(const float4*)&hp0I[k + 0][0];
        float4 h1 = *(const float4*)&hp0I[k + 1][0];
        float4 h2 = *(const float4*)&hp0I[k + 2][0];
        float4 h3 = *(const float4*)&hp0I[k + 3][0];
        a0 = __builtin_fmaf(h0.x, w0, a0); a1 = __builtin_fmaf(h0.y, w0, a1);
        a2 = __builtin_fmaf(h0.z, w0, a2); a3 = __builtin_fmaf(h0.w, w0, a3);
        a0 = __builtin_fmaf(h1.x, w1, a0); a1 = __builtin_fmaf(h1.y, w1, a1);
        a2 = __builtin_fmaf(h1.z, w1, a2); a3 = __builtin_fmaf(h1.w, w1, a3);
        a0 = __builtin_fmaf(h2.x, w2, a0); a1 = __builtin_fmaf(h2.y, w2, a1);
        a2 = __builtin_fmaf(h2.z, w2, a2); a3 = __builtin_fmaf(h2.w, w2, a3);
        a0 = __builtin_fmaf(h3.x, w3, a0); a1 = __builtin_fmaf(h3.y, w3, a1);
        a2 = __builtin_fmaf(h3.z, w3, a2); a3 = __builtin_fmaf(h3.w, w3, a3);
      }
      Qs[0][t] = a0; Qs[1][t] = a1; Qs[2][t] = a2; Qs[3][t] = a3;
    }
    __syncthreads();   // Qs ready

    // ---- U/z phase: quarter bb, lane tl = n. float4 K stream, 16 loads in
    // flight per group. k ascends 0..511 into l[k%16] — bit-exact R7 order.
    if (tl < NNODE) {
#pragma clang fp contract(off)
      float l[16];
#pragma unroll
      for (int j = 0; j < 16; j++) l[j] = 0.0f;
#pragma unroll 1
      for (int g = 0; g < 8; g++) {        // 8 groups of 64 k = 16 float4
        float4 kv[16];
#pragma unroll
        for (int m = 0; m < 16; m++)
          kv[m] = Kb4[(size_t)(g * 16 + m) * NNODE];
#pragma unroll
        for (int m = 0; m < 16; m++) {
          const int r = (4 * m) & 15;       // static residue base
          float p0 = kv[m].x * qrow[g * 64 + 4 * m + 0];
          l[r + 0] = l[r + 0] + p0;
          float p1 = kv[m].y * qrow[g * 64 + 4 * m + 1];
          l[r + 1] = l[r + 1] + p1;
          float p2 = kv[m].z * qrow[g * 64 + 4 * m + 2];
          l[r + 2] = l[r + 2] + p2;
          float p3 = kv[m].w * qrow[g * 64 + 4 * m + 3];
          l[r + 3] = l[r + 3] + p3;
        }
      }
      // shuffle-halving horizontal reduce over 16 lanes:
#pragma unroll
      for (int j = 0; j < 8; j++) l[j] = l[j] + l[j + 8];
#pragma unroll
      for (int j = 0; j < 4; j++) l[j] = l[j] + l[j + 4];
#pragma unroll
      for (int j = 0; j < 2; j++) l[j] = l[j] + l[j + 2];
      float U = l[0] + l[1];
      const float inv = 1.0f / sqrtf(512.0f);
      float u = U * inv;
      float logit = 10.0f * xla_tanh_f32(u);
      unsigned kk0, kk1;
      step_key(step, kk0, kk1);
      unsigned bits = elem_bits(kk0, kk1, (unsigned)(b * NNODE + tl));
      unsigned fb = (bits >> 9) | 0x3F800000u;
      float uf = __uint_as_float(fb) - 1.0f;    // [0,1), exact
      const float tinyf = 1.17549435e-38f;
      float v = uf * 1.0f;
      v = v + tinyf;
      v = fmaxf(tinyf, v);
      float L1 = xla_log_f32(v);
      float gmb = -xla_log_f32(-L1);
      zl[bb][tl] = gmb + logit;
    }
    __syncthreads();   // zl ready

    // ---- argmax: every wave reduces its quarter redundantly (no extra barrier)
    int pi;
    {
      float bv = -__builtin_inff();
      int bi = 0;
      for (int n = (tl & 63); n < NNODE; n += 64) {
        float zv = zl[bb][n];
        if (zv > bv) { bv = zv; bi = n; }
      }
      for (int off = 32; off; off >>= 1) {
        float ov = __shfl_down(bv, off);
        int   oi = __shfl_down(bi, off);
        if (ov > bv || (ov == bv && oi < bi)) { bv = ov; bi = oi; }
      }
      pi = __shfl(bi, 0);   // broadcast wave result (identical across waves)
    }
    if (tl == 0) {
      out[b * (NSTEP + 1) + step + 1] = pi;
      if (step == 0) out[b * (NSTEP + 1)] = pi;  // duplicated step-0 pick
    }
    {   // gather H[b, pi] into hpI (exact copy)
      const float* src = H + ((size_t)b * NNODE + pi) * DH;
      for (int e = tl; e < DH; e += 256) hpI[e][bb] = src[e];
    }
    __syncthreads();   // hpI ready
    if (step == 0) {   // freeze H_pi_1 = step-0 pick
      for (int e = t; e < DH * G; e += TPB) hp0I[e >> 2][e & 3] = hpI[e >> 2][e & 3];
      __syncthreads();
    }
  }
}

extern "C" void kernel_launch(void* const* d_in, const int* in_sizes, int n_in,
                              void* d_out, int out_size, void* d_ws, size_t ws_size,
                              hipStream_t stream) {
  (void)in_sizes; (void)n_in; (void)out_size; (void)ws_size;
  const float* H  = (const float*)d_in[1];
  const float* WQ = (const float*)d_in[2];
  const float* WK = (const float*)d_in[3];
  const float* v1 = (const float*)d_in[4];
  const float* vf = (const float*)d_in[5];
  int* out = (int*)d_out;

  float* ws = (float*)d_ws;
  const size_t KSZ = (size_t)BSZ * NNODE * DK;  // 419.4 MB
  const size_t S = (size_t)BSZ * 512;
  float* KT   = ws;
  float* Hbar = ws + KSZ;
  float* acc  = ws + KSZ + S;

  k_hbar  <<<2048, 256, 0, stream>>>(H, Hbar);
  k_K     <<<BSZ * 25, 256, 0, stream>>>(H, WK, KT);
  k_acc512<<<BSZ, 256, 0, stream>>>(Hbar, WQ, acc);
  k_mega  <<<BSZ / G, TPB, 0, stream>>>(KT, acc, WQ, H, v1, vf, out);
}

// Round 14
// 19650.388 us; speedup vs baseline: 4.9540x; 1.5058x over previous
//
#include <hip/hip_runtime.h>
#include <math.h>

#define BSZ 1024
#define NNODE 200
#define DH 512
#define DK 512
#define NSTEP 200
#define G 4       // batch rows per block
#define TPB 1024
#define NRES 86   // blocks 0..85: L3-resident K partition (~141 MB); rest nt

typedef float f4 __attribute__((ext_vector_type(4)));

// ---------------- threefry2x32 (JAX-exact, partitionable mode) ----------------
__device__ __forceinline__ unsigned rotl32(unsigned x, int r) {
  return (x << r) | (x >> (32 - r));
}

__device__ __forceinline__ void tf2x32(unsigned k0, unsigned k1,
                                       unsigned c0, unsigned c1,
                                       unsigned& o0, unsigned& o1) {
  unsigned ks2 = k0 ^ k1 ^ 0x1BD11BDAu;
  unsigned x0 = c0 + k0, x1 = c1 + k1;
#define TF_RND(r) { x0 += x1; x1 = rotl32(x1, (r)); x1 ^= x0; }
  TF_RND(13) TF_RND(15) TF_RND(26) TF_RND(6)
  x0 += k1;  x1 += ks2 + 1u;
  TF_RND(17) TF_RND(29) TF_RND(16) TF_RND(24)
  x0 += ks2; x1 += k0 + 2u;
  TF_RND(13) TF_RND(15) TF_RND(26) TF_RND(6)
  x0 += k0;  x1 += k1 + 3u;
  TF_RND(17) TF_RND(29) TF_RND(16) TF_RND(24)
  x0 += k1;  x1 += ks2 + 4u;
  TF_RND(13) TF_RND(15) TF_RND(26) TF_RND(6)
  x0 += ks2; x1 += k0 + 5u;
#undef TF_RND
  o0 = x0; o1 = x1;
}

__device__ __forceinline__ void step_key(int i, unsigned& k0, unsigned& k1) {
  tf2x32(0u, 42u, 0u, (unsigned)i, k0, k1);
}
__device__ __forceinline__ unsigned elem_bits(unsigned k0, unsigned k1, unsigned m) {
  unsigned o0, o1;
  tf2x32(k0, k1, 0u, m, o0, o1);
  return o0 ^ o1;
}

// -------- XLA f32 tanh (EmitFastTanh, with_fma=true -> fmuladd Horner) -------
__device__ __forceinline__ float xla_tanh_f32(float x) {
  const float kMax = 7.90531110763549805f;
  float xc = fminf(fmaxf(x, -kMax), kMax);
  float x2 = xc * xc;
  float p = -2.76076847742355e-16f;
  p = __builtin_fmaf(x2, p, 2.00018790482477e-13f);
  p = __builtin_fmaf(x2, p, -8.60467152213735e-11f);
  p = __builtin_fmaf(x2, p, 5.12229709037114e-08f);
  p = __builtin_fmaf(x2, p, 1.48572235717979e-05f);
  p = __builtin_fmaf(x2, p, 6.37261928875436e-04f);
  p = __builtin_fmaf(x2, p, 4.89352455891786e-03f);
  float num = xc * p;
  float q = 1.19825839466702e-06f;
  q = __builtin_fmaf(x2, q, 1.18534705686654e-04f);
  q = __builtin_fmaf(x2, q, 2.26843463243900e-03f);
  q = __builtin_fmaf(x2, q, 4.89352518554385e-03f);
  float r = num / q;
  return (fabsf(x) < 0.0004f) ? x : r;
}

// ---------------- XLA f32 log (Cephes, plain fmul/fadd as in VF32Log) --------
__device__ __forceinline__ float xla_log_f32(float x) {
#pragma clang fp contract(off)
  unsigned bits = __float_as_uint(x);
  int e = (int)((bits >> 23) & 0xffu) - 126;          // x = m * 2^e, m in [0.5,1)
  float m = __uint_as_float((bits & 0x007fffffu) | 0x3f000000u);
  bool c = m < 0.707106781186547524f;                 // sqrt(0.5)
  e = c ? (e - 1) : e;
  m = c ? (m + m) : m;
  m = m - 1.0f;
  float z = m * m;
  float y = 7.0376836292e-2f;
  y = y * m + (-1.1514610310e-1f);
  y = y * m + 1.1676998740e-1f;
  y = y * m + (-1.2420140846e-1f);
  y = y * m + 1.4249322787e-1f;
  y = y * m + (-1.6668057665e-1f);
  y = y * m + 2.0000714765e-1f;
  y = y * m + (-2.4999993993e-1f);
  y = y * m + 3.3333331174e-1f;
  y = y * m;
  y = y * z;
  float ef = (float)e;
  float t1 = ef * (-2.12194440e-4f);
  y = y + t1;
  float t2 = z * 0.5f;
  y = y - t2;
  float r = m + y;
  float t3 = ef * 0.693359375f;
  r = r + t3;
  return r;
}

// ---------------- U dot: W=16 mod-16 lane fold + shuffle tree (R7-exact) -----
template<bool NT>
__device__ __forceinline__ float u_dot(const f4* __restrict__ Kb4,
                                       const float* __restrict__ qrow) {
  float l[16];
#pragma unroll
  for (int j = 0; j < 16; j++) l[j] = 0.0f;
#pragma unroll 1
  for (int g = 0; g < 8; g++) {        // 8 groups of 64 k = 16 float4
    f4 kv[16];
#pragma unroll
    for (int m = 0; m < 16; m++) {
      const f4* p = &Kb4[(size_t)(g * 16 + m) * NNODE];
      kv[m] = NT ? __builtin_nontemporal_load(p) : *p;
    }
    {
#pragma clang fp contract(off)
#pragma unroll
      for (int m = 0; m < 16; m++) {
        const int r = (4 * m) & 15;       // static residue base
        float p0 = kv[m][0] * qrow[g * 64 + 4 * m + 0];
        l[r + 0] = l[r + 0] + p0;
        float p1 = kv[m][1] * qrow[g * 64 + 4 * m + 1];
        l[r + 1] = l[r + 1] + p1;
        float p2 = kv[m][2] * qrow[g * 64 + 4 * m + 2];
        l[r + 2] = l[r + 2] + p2;
        float p3 = kv[m][3] * qrow[g * 64 + 4 * m + 3];
        l[r + 3] = l[r + 3] + p3;
      }
    }
  }
  {
#pragma clang fp contract(off)
#pragma unroll
    for (int j = 0; j < 8; j++) l[j] = l[j] + l[j + 8];
#pragma unroll
    for (int j = 0; j < 4; j++) l[j] = l[j] + l[j + 4];
#pragma unroll
    for (int j = 0; j < 2; j++) l[j] = l[j] + l[j + 2];
    return l[0] + l[1];
  }
}

// ---------------- setup kernels (f32, gold-faithful orders) ----------------

__global__ void k_hbar(const float* __restrict__ H, float* __restrict__ Hbar) {
#pragma clang fp contract(off)
  int idx = blockIdx.x * 256 + threadIdx.x;  // 1024*512
  int b = idx >> 9, d = idx & 511;
  const float* p = H + (size_t)b * NNODE * DH + d;
  float s = 0.0f;
  for (int n = 0; n < NNODE; n++) s = s + p[(size_t)n * DH];
  Hbar[idx] = s / 200.0f;
}

// KT4[b][c][n][j] = K[b][n][4c+j], K = FMA-chain over d ascending (Eigen model).
__global__ __launch_bounds__(256) void k_K(const float* __restrict__ H,
                                           const float* __restrict__ WK,
                                           float* __restrict__ KT) {
  __shared__ float hr[8][DH];        // 16 KiB
  __shared__ float ts[DK * 9];       // retile pad-9, conflict-free
  int g = blockIdx.x;                // 1024*25 blocks, 8 rows each
  int b = g / 25;
  int r0 = (g % 25) * 8;
  int t = threadIdx.x;
  const float* Hb = H + (size_t)b * NNODE * DH + (size_t)r0 * DH;
  for (int e = t; e < 8 * DH; e += 256) hr[e >> 9][e & 511] = Hb[e];
  __syncthreads();
  int k0 = t, k1 = t + 256;
  float a[8][2];
#pragma unroll
  for (int r = 0; r < 8; r++) { a[r][0] = 0.0f; a[r][1] = 0.0f; }
  for (int d = 0; d < DH; d++) {
    float w0 = WK[(size_t)d * DK + k0], w1 = WK[(size_t)d * DK + k1];
#pragma unroll
    for (int r = 0; r < 8; r++) {
      a[r][0] = __builtin_fmaf(hr[r][d], w0, a[r][0]);
      a[r][1] = __builtin_fmaf(hr[r][d], w1, a[r][1]);
    }
  }
#pragma unroll
  for (int r = 0; r < 8; r++) {
    ts[k0 * 9 + r] = a[r][0];
    ts[k1 * 9 + r] = a[r][1];
  }
  __syncthreads();
  float* Ko = KT + (size_t)b * DK * NNODE;
  for (int i = t; i < (DK / 4) * 8; i += 256) {   // 1024 (c,r) pairs
    int c = i >> 3, r = i & 7;
    float4 v = make_float4(ts[(4 * c + 0) * 9 + r], ts[(4 * c + 1) * 9 + r],
                           ts[(4 * c + 2) * 9 + r], ts[(4 * c + 3) * 9 + r]);
    *(float4*)(Ko + ((size_t)c * NNODE + (r0 + r)) * 4) = v;
  }
}

// acc[b][j] = FMA-chain k=0..511 of Hbar[b,k]*WQ[k,j] (prefix of the 1536-chain)
__global__ __launch_bounds__(256) void k_acc512(const float* __restrict__ Hbar,
                                                const float* __restrict__ WQ,
                                                float* __restrict__ acc) {
  __shared__ float hb[DH];
  int b = blockIdx.x, t = threadIdx.x;
  for (int e = t; e < DH; e += 256) hb[e] = Hbar[(size_t)b * DH + e];
  __syncthreads();
  int j0 = t, j1 = t + 256;
  float a0 = 0.0f, a1 = 0.0f;
  for (int k = 0; k < DH; k++) {
    float w0 = WQ[(size_t)k * DK + j0], w1 = WQ[(size_t)k * DK + j1];
    a0 = __builtin_fmaf(hb[k], w0, a0);
    a1 = __builtin_fmaf(hb[k], w1, a1);
  }
  acc[(size_t)b * DK + j0] = a0;
  acc[(size_t)b * DK + j1] = a1;
}

// ---------------- the fused 200-step decoder: one block owns G batch rows ----
__global__ __launch_bounds__(TPB, 4) void k_mega(const float* __restrict__ KT,
                                                 const float* __restrict__ acc,
                                                 const float* __restrict__ WQ,
                                                 const float* __restrict__ H,
                                                 const float* __restrict__ v1,
                                                 const float* __restrict__ vf,
                                                 int* __restrict__ out) {
  __shared__ float hpI[DH][G];     // interleaved [k][bb] : current pick
  __shared__ float hp0I[DH][G];    // first pick (frozen after step 0)
  __shared__ float Qs[G][DK];
  __shared__ float accs[G][DK];
  __shared__ float zl[G][NNODE];
  int t = threadIdx.x;
  int b0 = blockIdx.x * G;
  int bb = t >> 8;                 // quarter owns batch row b0+bb
  int tl = t & 255;
  int b = b0 + bb;
  const bool useNT = (blockIdx.x >= NRES);   // L3-resident vs HBM-stream split
  const f4* Kb4 = (const f4*)(KT + (size_t)b * DK * NNODE) + tl;  // +n
  const float* qrow = &Qs[bb][0];

  for (int e = t; e < G * DK; e += TPB) {
    int b2 = e >> 9, j = e & 511;
    accs[b2][j] = acc[(size_t)(b0 + b2) * DK + j];
  }
  for (int e = t; e < DH; e += TPB) {
    float a = v1[e], bv = vf[e];
#pragma unroll
    for (int b2 = 0; b2 < G; b2++) { hpI[e][b2] = a; hp0I[e][b2] = bv; }
  }
  __syncthreads();

  for (int step = 0; step < NSTEP; step++) {
    // ---- Q phase (threads 0..511): thread owns column j=t; 4 chains.
    if (t < 512) {
      float a0 = accs[0][t], a1 = accs[1][t], a2 = accs[2][t], a3 = accs[3][t];
      const float* Wp = WQ + (size_t)512 * DK + t;
      for (int k = 0; k < DH; k += 4) {
        float w0 = Wp[(size_t)(k + 0) * DK];
        float w1 = Wp[(size_t)(k + 1) * DK];
        float w2 = Wp[(size_t)(k + 2) * DK];
        float w3 = Wp[(size_t)(k + 3) * DK];
        float4 h0 = *(const float4*)&hpI[k + 0][0];
        float4 h1 = *(const float4*)&hpI[k + 1][0];
        float4 h2 = *(const float4*)&hpI[k + 2][0];
        float4 h3 = *(const float4*)&hpI[k + 3][0];
        a0 = __builtin_fmaf(h0.x, w0, a0); a1 = __builtin_fmaf(h0.y, w0, a1);
        a2 = __builtin_fmaf(h0.z, w0, a2); a3 = __builtin_fmaf(h0.w, w0, a3);
        a0 = __builtin_fmaf(h1.x, w1, a0); a1 = __builtin_fmaf(h1.y, w1, a1);
        a2 = __builtin_fmaf(h1.z, w1, a2); a3 = __builtin_fmaf(h1.w, w1, a3);
        a0 = __builtin_fmaf(h2.x, w2, a0); a1 = __builtin_fmaf(h2.y, w2, a1);
        a2 = __builtin_fmaf(h2.z, w2, a2); a3 = __builtin_fmaf(h2.w, w2, a3);
        a0 = __builtin_fmaf(h3.x, w3, a0); a1 = __builtin_fmaf(h3.y, w3, a1);
        a2 = __builtin_fmaf(h3.z, w3, a2); a3 = __builtin_fmaf(h3.w, w3, a3);
      }
      const float* Wp2 = WQ + (size_t)1024 * DK + t;
      for (int k = 0; k < DH; k += 4) {
        float w0 = Wp2[(size_t)(k + 0) * DK];
        float w1 = Wp2[(size_t)(k + 1) * DK];
        float w2 = Wp2[(size_t)(k + 2) * DK];
        float w3 = Wp2[(size_t)(k + 3) * DK];
        float4 h0 = *(const float4*)&hp0I[k + 0][0];
        float4 h1 = *(const float4*)&hp0I[k + 1][0];
        float4 h2 = *(const float4*)&hp0I[k + 2][0];
        float4 h3 = *(const float4*)&hp0I[k + 3][0];
        a0 = __builtin_fmaf(h0.x, w0, a0); a1 = __builtin_fmaf(h0.y, w0, a1);
        a2 = __builtin_fmaf(h0.z, w0, a2); a3 = __builtin_fmaf(h0.w, w0, a3);
        a0 = __builtin_fmaf(h1.x, w1, a0); a1 = __builtin_fmaf(h1.y, w1, a1);
        a2 = __builtin_fmaf(h1.z, w1, a2); a3 = __builtin_fmaf(h1.w, w1, a3);
        a0 = __builtin_fmaf(h2.x, w2, a0); a1 = __builtin_fmaf(h2.y, w2, a1);
        a2 = __builtin_fmaf(h2.z, w2, a2); a3 = __builtin_fmaf(h2.w, w2, a3);
        a0 = __builtin_fmaf(h3.x, w3, a0); a1 = __builtin_fmaf(h3.y, w3, a1);
        a2 = __builtin_fmaf(h3.z, w3, a2); a3 = __builtin_fmaf(h3.w, w3, a3);
      }
      Qs[0][t] = a0; Qs[1][t] = a1; Qs[2][t] = a2; Qs[3][t] = a3;
    }
    __syncthreads();   // Qs ready

    // ---- U/z phase: quarter bb, lane tl = n. Bit-exact R7 fold order.
    if (tl < NNODE) {
      float U = useNT ? u_dot<true>(Kb4, qrow) : u_dot<false>(Kb4, qrow);
      {
#pragma clang fp contract(off)
        const float inv = 1.0f / sqrtf(512.0f);
        float u = U * inv;
        float logit = 10.0f * xla_tanh_f32(u);
        unsigned kk0, kk1;
        step_key(step, kk0, kk1);
        unsigned bits = elem_bits(kk0, kk1, (unsigned)(b * NNODE + tl));
        unsigned fb = (bits >> 9) | 0x3F800000u;
        float uf = __uint_as_float(fb) - 1.0f;    // [0,1), exact
        const float tinyf = 1.17549435e-38f;
        float v = uf * 1.0f;
        v = v + tinyf;
        v = fmaxf(tinyf, v);
        float L1 = xla_log_f32(v);
        float gmb = -xla_log_f32(-L1);
        zl[bb][tl] = gmb + logit;
      }
    }
    __syncthreads();   // zl ready

    // ---- argmax: every wave reduces its quarter redundantly (no extra barrier)
    int pi;
    {
      float bv = -__builtin_inff();
      int bi = 0;
      for (int n = (tl & 63); n < NNODE; n += 64) {
        float zv = zl[bb][n];
        if (zv > bv) { bv = zv; bi = n; }
      }
      for (int off = 32; off; off >>= 1) {
        float ov = __shfl_down(bv, off);
        int   oi = __shfl_down(bi, off);
        if (ov > bv || (ov == bv && oi < bi)) { bv = ov; bi = oi; }
      }
      pi = __shfl(bi, 0);   // broadcast wave result (identical across waves)
    }
    if (tl == 0) {
      out[b * (NSTEP + 1) + step + 1] = pi;
      if (step == 0) out[b * (NSTEP + 1)] = pi;  // duplicated step-0 pick
    }
    {   // gather H[b, pi] into hpI (exact copy)
      const float* src = H + ((size_t)b * NNODE + pi) * DH;
      for (int e = tl; e < DH; e += 256) hpI[e][bb] = src[e];
    }
    __syncthreads();   // hpI ready
    if (step == 0) {   // freeze H_pi_1 = step-0 pick
      for (int e = t; e < DH * G; e += TPB) hp0I[e >> 2][e & 3] = hpI[e >> 2][e & 3];
      __syncthreads();
    }
  }
}

extern "C" void kernel_launch(void* const* d_in, const int* in_sizes, int n_in,
                              void* d_out, int out_size, void* d_ws, size_t ws_size,
                              hipStream_t stream) {
  (void)in_sizes; (void)n_in; (void)out_size; (void)ws_size;
  const float* H  = (const float*)d_in[1];
  const float* WQ = (const float*)d_in[2];
  const float* WK = (const float*)d_in[3];
  const float* v1 = (const float*)d_in[4];
  const float* vf = (const float*)d_in[5];
  int* out = (int*)d_out;

  float* ws = (float*)d_ws;
  const size_t KSZ = (size_t)BSZ * NNODE * DK;  // 419.4 MB
  const size_t S = (size_t)BSZ * 512;
  float* KT   = ws;
  float* Hbar = ws + KSZ;
  float* acc  = ws + KSZ + S;

  k_hbar  <<<2048, 256, 0, stream>>>(H, Hbar);
  k_K     <<<BSZ * 25, 256, 0, stream>>>(H, WK, KT);
  k_acc512<<<BSZ, 256, 0, stream>>>(Hbar, WQ, acc);
  k_mega  <<<BSZ / G, TPB, 0, stream>>>(KT, acc, WQ, H, v1, vf, out);
}

// Round 15
// 19594.084 us; speedup vs baseline: 4.9683x; 1.0029x over previous
//
#include <hip/hip_runtime.h>
#include <math.h>

#define BSZ 1024
#define NNODE 200
#define DH 512
#define DK 512
#define NSTEP 200
#define G 4       // batch rows per block
#define TPB 1024
#define NRES 150  // blocks 0..149: L3-resident K partition (~245 MB); rest nt

typedef float f4 __attribute__((ext_vector_type(4)));

// ---------------- threefry2x32 (JAX-exact, partitionable mode) ----------------
__device__ __forceinline__ unsigned rotl32(unsigned x, int r) {
  return (x << r) | (x >> (32 - r));
}

__device__ __forceinline__ void tf2x32(unsigned k0, unsigned k1,
                                       unsigned c0, unsigned c1,
                                       unsigned& o0, unsigned& o1) {
  unsigned ks2 = k0 ^ k1 ^ 0x1BD11BDAu;
  unsigned x0 = c0 + k0, x1 = c1 + k1;
#define TF_RND(r) { x0 += x1; x1 = rotl32(x1, (r)); x1 ^= x0; }
  TF_RND(13) TF_RND(15) TF_RND(26) TF_RND(6)
  x0 += k1;  x1 += ks2 + 1u;
  TF_RND(17) TF_RND(29) TF_RND(16) TF_RND(24)
  x0 += ks2; x1 += k0 + 2u;
  TF_RND(13) TF_RND(15) TF_RND(26) TF_RND(6)
  x0 += k0;  x1 += k1 + 3u;
  TF_RND(17) TF_RND(29) TF_RND(16) TF_RND(24)
  x0 += k1;  x1 += ks2 + 4u;
  TF_RND(13) TF_RND(15) TF_RND(26) TF_RND(6)
  x0 += ks2; x1 += k0 + 5u;
#undef TF_RND
  o0 = x0; o1 = x1;
}

__device__ __forceinline__ void step_key(int i, unsigned& k0, unsigned& k1) {
  tf2x32(0u, 42u, 0u, (unsigned)i, k0, k1);
}
__device__ __forceinline__ unsigned elem_bits(unsigned k0, unsigned k1, unsigned m) {
  unsigned o0, o1;
  tf2x32(k0, k1, 0u, m, o0, o1);
  return o0 ^ o1;
}

// -------- XLA f32 tanh (EmitFastTanh, with_fma=true -> fmuladd Horner) -------
__device__ __forceinline__ float xla_tanh_f32(float x) {
  const float kMax = 7.90531110763549805f;
  float xc = fminf(fmaxf(x, -kMax), kMax);
  float x2 = xc * xc;
  float p = -2.76076847742355e-16f;
  p = __builtin_fmaf(x2, p, 2.00018790482477e-13f);
  p = __builtin_fmaf(x2, p, -8.60467152213735e-11f);
  p = __builtin_fmaf(x2, p, 5.12229709037114e-08f);
  p = __builtin_fmaf(x2, p, 1.48572235717979e-05f);
  p = __builtin_fmaf(x2, p, 6.37261928875436e-04f);
  p = __builtin_fmaf(x2, p, 4.89352455891786e-03f);
  float num = xc * p;
  float q = 1.19825839466702e-06f;
  q = __builtin_fmaf(x2, q, 1.18534705686654e-04f);
  q = __builtin_fmaf(x2, q, 2.26843463243900e-03f);
  q = __builtin_fmaf(x2, q, 4.89352518554385e-03f);
  float r = num / q;
  return (fabsf(x) < 0.0004f) ? x : r;
}

// ---------------- XLA f32 log (Cephes, plain fmul/fadd as in VF32Log) --------
__device__ __forceinline__ float xla_log_f32(float x) {
#pragma clang fp contract(off)
  unsigned bits = __float_as_uint(x);
  int e = (int)((bits >> 23) & 0xffu) - 126;          // x = m * 2^e, m in [0.5,1)
  float m = __uint_as_float((bits & 0x007fffffu) | 0x3f000000u);
  bool c = m < 0.707106781186547524f;                 // sqrt(0.5)
  e = c ? (e - 1) : e;
  m = c ? (m + m) : m;
  m = m - 1.0f;
  float z = m * m;
  float y = 7.0376836292e-2f;
  y = y * m + (-1.1514610310e-1f);
  y = y * m + 1.1676998740e-1f;
  y = y * m + (-1.2420140846e-1f);
  y = y * m + 1.4249322787e-1f;
  y = y * m + (-1.6668057665e-1f);
  y = y * m + 2.0000714765e-1f;
  y = y * m + (-2.4999993993e-1f);
  y = y * m + 3.3333331174e-1f;
  y = y * m;
  y = y * z;
  float ef = (float)e;
  float t1 = ef * (-2.12194440e-4f);
  y = y + t1;
  float t2 = z * 0.5f;
  y = y - t2;
  float r = m + y;
  float t3 = ef * 0.693359375f;
  r = r + t3;
  return r;
}

// ---------------- U dot: W=16 mod-16 lane fold + shuffle tree (R7-exact) -----
template<bool NT>
__device__ __forceinline__ float u_dot(const f4* __restrict__ Kb4,
                                       const float* __restrict__ qrow) {
  float l[16];
#pragma unroll
  for (int j = 0; j < 16; j++) l[j] = 0.0f;
#pragma unroll 1
  for (int g = 0; g < 8; g++) {        // 8 groups of 64 k = 16 float4
    f4 kv[16];
#pragma unroll
    for (int m = 0; m < 16; m++) {
      const f4* p = &Kb4[(size_t)(g * 16 + m) * NNODE];
      kv[m] = NT ? __builtin_nontemporal_load(p) : *p;
    }
    {
#pragma clang fp contract(off)
#pragma unroll
      for (int m = 0; m < 16; m++) {
        const int r = (4 * m) & 15;       // static residue base
        float p0 = kv[m][0] * qrow[g * 64 + 4 * m + 0];
        l[r + 0] = l[r + 0] + p0;
        float p1 = kv[m][1] * qrow[g * 64 + 4 * m + 1];
        l[r + 1] = l[r + 1] + p1;
        float p2 = kv[m][2] * qrow[g * 64 + 4 * m + 2];
        l[r + 2] = l[r + 2] + p2;
        float p3 = kv[m][3] * qrow[g * 64 + 4 * m + 3];
        l[r + 3] = l[r + 3] + p3;
      }
    }
  }
  {
#pragma clang fp contract(off)
#pragma unroll
    for (int j = 0; j < 8; j++) l[j] = l[j] + l[j + 8];
#pragma unroll
    for (int j = 0; j < 4; j++) l[j] = l[j] + l[j + 4];
#pragma unroll
    for (int j = 0; j < 2; j++) l[j] = l[j] + l[j + 2];
    return l[0] + l[1];
  }
}

// ---------------- setup kernels (f32, gold-faithful orders) ----------------

__global__ void k_hbar(const float* __restrict__ H, float* __restrict__ Hbar) {
#pragma clang fp contract(off)
  int idx = blockIdx.x * 256 + threadIdx.x;  // 1024*512
  int b = idx >> 9, d = idx & 511;
  const float* p = H + (size_t)b * NNODE * DH + d;
  float s = 0.0f;
  for (int n = 0; n < NNODE; n++) s = s + p[(size_t)n * DH];
  Hbar[idx] = s / 200.0f;
}

// KT4[b][c][n][j] = K[b][n][4c+j], K = FMA-chain over d ascending (Eigen model).
__global__ __launch_bounds__(256) void k_K(const float* __restrict__ H,
                                           const float* __restrict__ WK,
                                           float* __restrict__ KT) {
  __shared__ float hr[8][DH];        // 16 KiB
  __shared__ float ts[DK * 9];       // retile pad-9, conflict-free
  int g = blockIdx.x;                // 1024*25 blocks, 8 rows each
  int b = g / 25;
  int r0 = (g % 25) * 8;
  int t = threadIdx.x;
  const float* Hb = H + (size_t)b * NNODE * DH + (size_t)r0 * DH;
  for (int e = t; e < 8 * DH; e += 256) hr[e >> 9][e & 511] = Hb[e];
  __syncthreads();
  int k0 = t, k1 = t + 256;
  float a[8][2];
#pragma unroll
  for (int r = 0; r < 8; r++) { a[r][0] = 0.0f; a[r][1] = 0.0f; }
  for (int d = 0; d < DH; d++) {
    float w0 = WK[(size_t)d * DK + k0], w1 = WK[(size_t)d * DK + k1];
#pragma unroll
    for (int r = 0; r < 8; r++) {
      a[r][0] = __builtin_fmaf(hr[r][d], w0, a[r][0]);
      a[r][1] = __builtin_fmaf(hr[r][d], w1, a[r][1]);
    }
  }
#pragma unroll
  for (int r = 0; r < 8; r++) {
    ts[k0 * 9 + r] = a[r][0];
    ts[k1 * 9 + r] = a[r][1];
  }
  __syncthreads();
  float* Ko = KT + (size_t)b * DK * NNODE;
  for (int i = t; i < (DK / 4) * 8; i += 256) {   // 1024 (c,r) pairs
    int c = i >> 3, r = i & 7;
    float4 v = make_float4(ts[(4 * c + 0) * 9 + r], ts[(4 * c + 1) * 9 + r],
                           ts[(4 * c + 2) * 9 + r], ts[(4 * c + 3) * 9 + r]);
    *(float4*)(Ko + ((size_t)c * NNODE + (r0 + r)) * 4) = v;
  }
}

// acc[b][j] = FMA-chain k=0..511 of Hbar[b,k]*WQ[k,j] (prefix of the 1536-chain)
__global__ __launch_bounds__(256) void k_acc512(const float* __restrict__ Hbar,
                                                const float* __restrict__ WQ,
                                                float* __restrict__ acc) {
  __shared__ float hb[DH];
  int b = blockIdx.x, t = threadIdx.x;
  for (int e = t; e < DH; e += 256) hb[e] = Hbar[(size_t)b * DH + e];
  __syncthreads();
  int j0 = t, j1 = t + 256;
  float a0 = 0.0f, a1 = 0.0f;
  for (int k = 0; k < DH; k++) {
    float w0 = WQ[(size_t)k * DK + j0], w1 = WQ[(size_t)k * DK + j1];
    a0 = __builtin_fmaf(hb[k], w0, a0);
    a1 = __builtin_fmaf(hb[k], w1, a1);
  }
  acc[(size_t)b * DK + j0] = a0;
  acc[(size_t)b * DK + j1] = a1;
}

// ---------------- the fused 200-step decoder: one block owns G batch rows ----
__global__ __launch_bounds__(TPB, 4) void k_mega(const float* __restrict__ KT,
                                                 const float* __restrict__ acc,
                                                 const float* __restrict__ WQ,
                                                 const float* __restrict__ H,
                                                 const float* __restrict__ v1,
                                                 const float* __restrict__ vf,
                                                 int* __restrict__ out) {
  __shared__ float hpI[DH][G];     // interleaved [k][bb] : current pick
  __shared__ float hp0I[DH][G];    // first pick (frozen after step 0)
  __shared__ float Qs[G][DK];
  __shared__ float accs[G][DK];
  __shared__ float zl[G][NNODE];
  int t = threadIdx.x;
  int b0 = blockIdx.x * G;
  int bb = t >> 8;                 // quarter owns batch row b0+bb
  int tl = t & 255;
  int b = b0 + bb;
  const bool useNT = (blockIdx.x >= NRES);   // L3-resident vs HBM-stream split
  const f4* Kb4 = (const f4*)(KT + (size_t)b * DK * NNODE) + tl;  // +n
  const float* qrow = &Qs[bb][0];
  int qj = t & 511;                // Q-phase column
  int qb = (t >> 9) * 2;           // Q-phase bb base: 0 or 2

  for (int e = t; e < G * DK; e += TPB) {
    int b2 = e >> 9, j = e & 511;
    accs[b2][j] = acc[(size_t)(b0 + b2) * DK + j];
  }
  for (int e = t; e < DH; e += TPB) {
    float a = v1[e], bv = vf[e];
#pragma unroll
    for (int b2 = 0; b2 < G; b2++) { hpI[e][b2] = a; hp0I[e][b2] = bv; }
  }
  __syncthreads();

  for (int step = 0; step < NSTEP; step++) {
    // ---- Q phase (ALL threads): thread owns column qj for bb = qb, qb+1.
    {
      float a0 = accs[qb][qj], a1 = accs[qb + 1][qj];
      const float* Wp = WQ + (size_t)512 * DK + qj;
      for (int k = 0; k < DH; k += 4) {
        float w0 = Wp[(size_t)(k + 0) * DK];
        float w1 = Wp[(size_t)(k + 1) * DK];
        float w2 = Wp[(size_t)(k + 2) * DK];
        float w3 = Wp[(size_t)(k + 3) * DK];
        float2 h0 = *(const float2*)&hpI[k + 0][qb];
        float2 h1 = *(const float2*)&hpI[k + 1][qb];
        float2 h2 = *(const float2*)&hpI[k + 2][qb];
        float2 h3 = *(const float2*)&hpI[k + 3][qb];
        a0 = __builtin_fmaf(h0.x, w0, a0); a1 = __builtin_fmaf(h0.y, w0, a1);
        a0 = __builtin_fmaf(h1.x, w1, a0); a1 = __builtin_fmaf(h1.y, w1, a1);
        a0 = __builtin_fmaf(h2.x, w2, a0); a1 = __builtin_fmaf(h2.y, w2, a1);
        a0 = __builtin_fmaf(h3.x, w3, a0); a1 = __builtin_fmaf(h3.y, w3, a1);
      }
      const float* Wp2 = WQ + (size_t)1024 * DK + qj;
      for (int k = 0; k < DH; k += 4) {
        float w0 = Wp2[(size_t)(k + 0) * DK];
        float w1 = Wp2[(size_t)(k + 1) * DK];
        float w2 = Wp2[(size_t)(k + 2) * DK];
        float w3 = Wp2[(size_t)(k + 3) * DK];
        float2 h0 = *(const float2*)&hp0I[k + 0][qb];
        float2 h1 = *(const float2*)&hp0I[k + 1][qb];
        float2 h2 = *(const float2*)&hp0I[k + 2][qb];
        float2 h3 = *(const float2*)&hp0I[k + 3][qb];
        a0 = __builtin_fmaf(h0.x, w0, a0); a1 = __builtin_fmaf(h0.y, w0, a1);
        a0 = __builtin_fmaf(h1.x, w1, a0); a1 = __builtin_fmaf(h1.y, w1, a1);
        a0 = __builtin_fmaf(h2.x, w2, a0); a1 = __builtin_fmaf(h2.y, w2, a1);
        a0 = __builtin_fmaf(h3.x, w3, a0); a1 = __builtin_fmaf(h3.y, w3, a1);
      }
      Qs[qb][qj] = a0; Qs[qb + 1][qj] = a1;
    }
    __syncthreads();   // Qs ready

    // ---- U/z phase: quarter bb, lane tl = n. Bit-exact R7 fold order.
    if (tl < NNODE) {
      float U = useNT ? u_dot<true>(Kb4, qrow) : u_dot<false>(Kb4, qrow);
      {
#pragma clang fp contract(off)
        const float inv = 1.0f / sqrtf(512.0f);
        float u = U * inv;
        float logit = 10.0f * xla_tanh_f32(u);
        unsigned kk0, kk1;
        step_key(step, kk0, kk1);
        unsigned bits = elem_bits(kk0, kk1, (unsigned)(b * NNODE + tl));
        unsigned fb = (bits >> 9) | 0x3F800000u;
        float uf = __uint_as_float(fb) - 1.0f;    // [0,1), exact
        const float tinyf = 1.17549435e-38f;
        float v = uf * 1.0f;
        v = v + tinyf;
        v = fmaxf(tinyf, v);
        float L1 = xla_log_f32(v);
        float gmb = -xla_log_f32(-L1);
        zl[bb][tl] = gmb + logit;
      }
    }
    __syncthreads();   // zl ready

    // ---- argmax: every wave reduces its quarter redundantly (no extra barrier)
    int pi;
    {
      float bv = -__builtin_inff();
      int bi = 0;
      for (int n = (tl & 63); n < NNODE; n += 64) {
        float zv = zl[bb][n];
        if (zv > bv) { bv = zv; bi = n; }
      }
      for (int off = 32; off; off >>= 1) {
        float ov = __shfl_down(bv, off);
        int   oi = __shfl_down(bi, off);
        if (ov > bv || (ov == bv && oi < bi)) { bv = ov; bi = oi; }
      }
      pi = __shfl(bi, 0);   // broadcast wave result (identical across waves)
    }
    if (tl == 0) {
      out[b * (NSTEP + 1) + step + 1] = pi;
      if (step == 0) out[b * (NSTEP + 1)] = pi;  // duplicated step-0 pick
    }
    {   // gather H[b, pi] into hpI (exact copy)
      const float* src = H + ((size_t)b * NNODE + pi) * DH;
      for (int e = tl; e < DH; e += 256) hpI[e][bb] = src[e];
    }
    __syncthreads();   // hpI ready
    if (step == 0) {   // freeze H_pi_1 = step-0 pick
      for (int e = t; e < DH * G; e += TPB) hp0I[e >> 2][e & 3] = hpI[e >> 2][e & 3];
      __syncthreads();
    }
  }
}

extern "C" void kernel_launch(void* const* d_in, const int* in_sizes, int n_in,
                              void* d_out, int out_size, void* d_ws, size_t ws_size,
                              hipStream_t stream) {
  (void)in_sizes; (void)n_in; (void)out_size; (void)ws_size;
  const float* H  = (const float*)d_in[1];
  const float* WQ = (const float*)d_in[2];
  const float* WK = (const float*)d_in[3];
  const float* v1 = (const float*)d_in[4];
  const float* vf = (const float*)d_in[5];
  int* out = (int*)d_out;

  float* ws = (float*)d_ws;
  const size_t KSZ = (size_t)BSZ * NNODE * DK;  // 419.4 MB
  const size_t S = (size_t)BSZ * 512;
  float* KT   = ws;
  float* Hbar = ws + KSZ;
  float* acc  = ws + KSZ + S;

  k_hbar  <<<2048, 256, 0, stream>>>(H, Hbar);
  k_K     <<<BSZ * 25, 256, 0, stream>>>(H, WK, KT);
  k_acc512<<<BSZ, 256, 0, stream>>>(Hbar, WQ, acc);
  k_mega  <<<BSZ / G, TPB, 0, stream>>>(KT, acc, WQ, H, v1, vf, out);
}